// Round 1
// baseline (1187.921 us; speedup 1.0000x reference)
//
#include <hip/hip_runtime.h>
#include <stdint.h>

// Problem constants (fixed by the reference)
#define NROWS 1000000
#define DDIM  128
#define NCLS  1000
#define NGRP  8            // class groups
#define CPG   125          // classes per group (1000/8)
#define NCHUNK 64          // row chunks; grid = NCHUNK x NGRP = 512 blocks = 2/CU

// ws layout (floats):
//   [0, 128000)        gsum   (c*128 + d)
//   [128000, 129000)   gcount
//   [129000]           var accumulator
#define WS_FLOATS 129001

__global__ void zero_ws_kernel(float* __restrict__ ws) {
    int i = blockIdx.x * 256 + threadIdx.x;
    if (i < WS_FLOATS) ws[i] = 0.0f;
}

// Segment sums, class-group partitioned, LDS-privatized.
__global__ __launch_bounds__(512, 4) void seg_sum_kernel(
        const float* __restrict__ emb, const int* __restrict__ labels,
        float* __restrict__ gsum, float* __restrict__ gcount) {
    __shared__ float lsum[CPG * DDIM];   // 64000 B
    __shared__ float lcount[CPG];        // 500 B

    const int g     = blockIdx.y;
    const int chunk = blockIdx.x;
    const int c_lo  = g * CPG;

    for (int i = threadIdx.x; i < CPG * DDIM; i += 512) lsum[i] = 0.0f;
    for (int i = threadIdx.x; i < CPG; i += 512) lcount[i] = 0.0f;
    __syncthreads();

    const int rows_per_chunk = NROWS / NCHUNK;          // 15625
    const int r0 = chunk * rows_per_chunk;
    const int r1 = r0 + rows_per_chunk;
    const int wave = threadIdx.x >> 6;
    const int lane = threadIdx.x & 63;

    for (int base = r0 + wave * 64; base < r1; base += 512) {
        int r   = base + lane;
        int lbl = (r < r1) ? labels[r] : -1;
        int lc  = lbl - c_lo;
        bool in_g = (lc >= 0) && (lc < CPG);
        unsigned long long mask = __ballot(in_g);

        while (mask) {
            // pop up to 4 matched rows -> independent in-flight loads (MLP)
            int b[4];
            #pragma unroll
            for (int k = 0; k < 4; k++) {
                if (mask) {
                    b[k] = (int)__builtin_ctzll(mask);
                    mask &= mask - 1;
                } else {
                    b[k] = -1;
                }
            }
            float v0[4], v1[4];
            int cc[4];
            #pragma unroll
            for (int k = 0; k < 4; k++) {
                if (b[k] >= 0) {
                    cc[k] = __shfl(lc, b[k]);
                    const float* rp = emb + (size_t)(base + b[k]) * DDIM;
                    v0[k] = rp[lane];        // dims [0,64): bank = lane%32, 2-way free
                    v1[k] = rp[lane + 64];   // dims [64,128)
                }
            }
            #pragma unroll
            for (int k = 0; k < 4; k++) {
                if (b[k] >= 0) {
                    atomicAdd(&lsum[cc[k] * DDIM + lane], v0[k]);
                    atomicAdd(&lsum[cc[k] * DDIM + 64 + lane], v1[k]);
                    if (lane == 0) atomicAdd(&lcount[cc[k]], 1.0f);
                }
            }
        }
    }
    __syncthreads();

    // flush LDS partials to global (atomic; 512 KB target stays L2-resident)
    for (int i = threadIdx.x; i < CPG * DDIM; i += 512) {
        float v = lsum[i];
        if (v != 0.0f) atomicAdd(&gsum[c_lo * DDIM + i], v);
    }
    for (int i = threadIdx.x; i < CPG; i += 512) {
        float v = lcount[i];
        if (v != 0.0f) atomicAdd(&gcount[c_lo + i], v);
    }
}

// One block per dim d: variance over 1000 class means (ddof=1), accumulate.
__global__ void var_kernel(const float* __restrict__ gsum,
                           const float* __restrict__ gcount,
                           float* __restrict__ acc) {
    const int d = blockIdx.x;
    float s1 = 0.0f, s2 = 0.0f;
    for (int c = threadIdx.x; c < NCLS; c += 256) {
        float m = gsum[c * DDIM + d] / gcount[c];
        s1 += m;
        s2 += m * m;
    }
    #pragma unroll
    for (int off = 32; off; off >>= 1) {
        s1 += __shfl_down(s1, off);
        s2 += __shfl_down(s2, off);
    }
    __shared__ float p1[4], p2[4];
    int wave = threadIdx.x >> 6, lane = threadIdx.x & 63;
    if (lane == 0) { p1[wave] = s1; p2[wave] = s2; }
    __syncthreads();
    if (threadIdx.x == 0) {
        float t1 = p1[0] + p1[1] + p1[2] + p1[3];
        float t2 = p2[0] + p2[1] + p2[2] + p2[3];
        float var = (t2 - t1 * t1 / (float)NCLS) / (float)(NCLS - 1);
        atomicAdd(acc, var);
    }
}

__global__ void final_kernel(const float* __restrict__ acc, float* __restrict__ out) {
    out[0] = -acc[0] / (float)DDIM;
}

extern "C" void kernel_launch(void* const* d_in, const int* in_sizes, int n_in,
                              void* d_out, int out_size, void* d_ws, size_t ws_size,
                              hipStream_t stream) {
    const float* emb    = (const float*)d_in[0];
    const int*   labels = (const int*)d_in[1];
    float* ws     = (float*)d_ws;
    float* gsum   = ws;
    float* gcount = ws + 128000;
    float* acc    = ws + 129000;
    float* out    = (float*)d_out;

    hipLaunchKernelGGL(zero_ws_kernel, dim3((WS_FLOATS + 255) / 256), dim3(256), 0, stream, ws);
    hipLaunchKernelGGL(seg_sum_kernel, dim3(NCHUNK, NGRP), dim3(512), 0, stream,
                       emb, labels, gsum, gcount);
    hipLaunchKernelGGL(var_kernel, dim3(DDIM), dim3(256), 0, stream, gsum, gcount, acc);
    hipLaunchKernelGGL(final_kernel, dim3(1), dim3(1), 0, stream, acc, out);
}